// Round 5
// baseline (3039.371 us; speedup 1.0000x reference)
//
#include <hip/hip_runtime.h>
#include <hip/hip_bf16.h>
#include <cstdint>
#include <cstddef>

// ---------------------------------------------------------------------------
// VQ-VAE forward (B=2048, L=100, D=64, K=64, CB=512) — im2col GEMM edition.
// All convs are GEMMs with M = B*NPOS (samples batched into M-tiles of 128).
// Encoder: split-bf16 (hi+lo) MFMA, 3 products -> ~f32 accuracy.
// Decoder: plain bf16 MFMA. Argmin exactness: margin 0.1 -> f64 recompute.
// Activations stored as bf16 planes (encoder: hi+lo, decoder: hi only).
// ---------------------------------------------------------------------------

typedef __attribute__((ext_vector_type(8))) short short8v;   // 8 bf16 (4 VGPR)
typedef __attribute__((ext_vector_type(4))) float f32x4;

constexpr int B  = 2048;
constexpr int L  = 100;
constexpr int K  = 64;
constexpr int CB = 512;
#define MARGIN 0.1f

// ---- workspace layout (float offsets) ----
// R0 [0, 51380224): A1 planes -> XE f32 -> G1+G2
// R1 [51380224, 84934656): A2 planes
constexpr size_t A1H_OFF = 0;          // 21233664 ushorts (10616832 f)
constexpr size_t A1L_OFF = 10616832;
constexpr size_t XE_OFF  = 0;          // 51380224 f32
constexpr size_t G1_OFF  = 0;          // 33554432 ushorts (16777216 f)
constexpr size_t G2_OFF  = 16777216;   // 21233664 ushorts
constexpr size_t A2H_OFF = 51380224;   // 33554432 ushorts (16777216 f)
constexpr size_t A2L_OFF = 68157440;
constexpr size_t IDX_OFF = 84934656;   // 2048*49 ints
constexpr size_t UBT_OFF = 85035008;   // 512*64 f32 transposed codebook
constexpr size_t CBN_OFF = 85067776;   // 64 norms
constexpr size_t CNT_OFF = 85067840;
constexpr size_t ACC_OFF = 85067856;
constexpr size_t WL_OFF  = 85067872;   // 100352 ints
constexpr size_t WB_OFF  = 85168224;   // bf16 weights (ushort units below)

// bf16 weight sub-offsets (ushort units), layout [4][OC][IC]
constexpr size_t EW1H=0,       EW1L=32768;
constexpr size_t EW2H=65536,   EW2L=196608;
constexpr size_t EW3H=327680,  EW3L=851968;
constexpr size_t DW1H=1376256, DW2H=1900544, DW3H=2031616;
constexpr size_t BKB =2064384;  // book bf16 [64][512]

__device__ inline ushort bf16_hi(float f){ __hip_bfloat16 h=__float2bfloat16(f); return *(ushort*)&h; }
__device__ inline float  bf16_tof(ushort u){ __hip_bfloat16 h; *(ushort*)&h=u; return __bfloat162float(h); }

// ---------------------------------------------------------------------------
// weight prep: w[2,2,IC,OC] f32 -> Wt[kk][oc][ic] bf16 hi (+lo for encoder);
// also book -> bf16.
// ---------------------------------------------------------------------------
__device__ void wtrans(const float* __restrict__ w, int IC, int OC,
                       ushort* __restrict__ hi, ushort* __restrict__ lo,
                       int gid, int gsz)
{
    int tot = 4*IC*OC;
    for (int i = gid; i < tot; i += gsz) {
        int kk = i/(IC*OC), r = i - kk*(IC*OC), ic = r/OC, oc = r - ic*OC;
        float v = w[i];
        ushort h = bf16_hi(v);
        size_t dst = ((size_t)kk*OC + oc)*IC + ic;
        hi[dst] = h;
        if (lo) lo[dst] = bf16_hi(v - bf16_tof(h));
    }
}

__global__ __launch_bounds__(256)
void wprep_k(const float* e1, const float* e2, const float* e3,
             const float* d1, const float* d2, const float* d3,
             const float* book, ushort* wb)
{
    int gid = blockIdx.x*256 + threadIdx.x, gsz = gridDim.x*256;
    wtrans(e1,  64, 128, wb+EW1H, wb+EW1L, gid, gsz);
    wtrans(e2, 128, 256, wb+EW2H, wb+EW2L, gid, gsz);
    wtrans(e3, 256, 512, wb+EW3H, wb+EW3L, gid, gsz);
    wtrans(d1, 512, 256, wb+DW1H, nullptr, gid, gsz);
    wtrans(d2, 256, 128, wb+DW2H, nullptr, gid, gsz);
    wtrans(d3, 128,  64, wb+DW3H, nullptr, gid, gsz);
    for (int i = gid; i < 64*512; i += gsz) wb[BKB+i] = bf16_hi(book[i]);
}

// ---------------------------------------------------------------------------
// im2col GEMM conv. M = B*NPOS rows (BM=128/block), N = OC (BN/block via
// grid.y), K = 4 taps x IC (64-elem chunks). 4 waves in WMxWN grid, each
// wave WROWSxWCOLS output via 16x16x32 bf16 MFMA.
// A staged to LDS per chunk (XOR-swizzled, bank-conflict-free), 2-phase
// pipelined: global loads for chunk c+1 issue before MFMAs of chunk c.
// MODE 0: activation planes; 1: embedding-table gather (f32->hi/lo cvt);
// MODE 2: bookbf gather via qidx.
// OUTFMT 0: f32; 1: bf16 hi/lo planes; 2: bf16.
// ---------------------------------------------------------------------------
template<int IH,int IW,int IC,int OC,int PAD,int MODE,bool HASBN,bool SPLIT,
         int BN,int WM,int WN,int OUTFMT>
__global__ __launch_bounds__(256)
void gconv_k(const ushort* __restrict__ a_hi, const ushort* __restrict__ a_lo,
             const int* __restrict__ ids, const int* __restrict__ masks,
             const float* __restrict__ table,
             const int* __restrict__ qidx, const ushort* __restrict__ bookbf,
             const ushort* __restrict__ wt_hi, const ushort* __restrict__ wt_lo,
             const float* __restrict__ bias, const float* __restrict__ gamma,
             const float* __restrict__ beta,
             float* __restrict__ out_f, ushort* __restrict__ out_hi,
             ushort* __restrict__ out_lo)
{
    constexpr int BM=128, RB=128;                 // rows/block, LDS row bytes
    constexpr int OH=IH+2*PAD-1, OW=IW+2*PAD-1, NPOS=OH*OW, IHW=IH*IW;
    constexpr int ICN=IC/64, NCH=4*ICN;
    constexpr int WROWS=BM/WM, WCOLS=BN/WN;
    constexpr int MT=WROWS/16, NT=WCOLS/16;
    constexpr int PL=SPLIT?2:1;
    constexpr int SREGS=SPLIT?8:4;

    __shared__ ushort s_a[PL*BM*64];
    char* sb=(char*)s_a;

    const int tid=threadIdx.x, lane=tid&63, wv=tid>>6;
    const int wr=wv/WN, wc=wv%WN;
    const int l15=lane&15, lq=lane>>4, l7=l15&7;
    const int m0g=blockIdx.x*BM;
    const int n0g=blockIdx.y*BN + wc*WCOLS;

    f32x4 acc[MT][NT];
    #pragma unroll
    for(int m=0;m<MT;++m)
        #pragma unroll
        for(int n=0;n<NT;++n) acc[m][n]=(f32x4)0.0f;

    uint4 sreg[SREGS];
    const uint4 z4 = make_uint4(0,0,0,0);

    auto stage_load=[&](int c){
        const int kk=c/ICN, ic0=(c-(c/ICN)*ICN)*64;
        const int ky=kk>>1, kx=kk&1;
        #pragma unroll
        for(int t=0;t<4;++t){
            int idx=tid+t*256;                 // plane-0 index space
            int row=idx>>3, slot=idx&7;
            int g=m0g+row;
            int b=g/NPOS, p=g-b*NPOS;
            int py=p/OW, px=p-py*OW;
            int ty=py+ky-PAD, tx=px+kx-PAD;
            bool ok=((unsigned)ty<(unsigned)IH)&&((unsigned)tx<(unsigned)IW);
            if constexpr(MODE==0){
                size_t off=((size_t)(b*IHW + (ok?(ty*IW+tx):0))*IC + ic0 + slot*8);
                sreg[t]= ok ? *(const uint4*)(a_hi+off) : z4;
                if constexpr(SPLIT) sreg[t+4]= ok ? *(const uint4*)(a_lo+off) : z4;
            } else if constexpr(MODE==1){
                int cell=ty*IW+tx;             // PAD=0: always valid
                int id=ids[b*L+cell];
                float msc=(masks[b*L+cell]>=1)?1.f:0.f;
                const float* src=table + (size_t)id*64 + ic0 + slot*8;
                float4 v0=*(const float4*)src, v1=*(const float4*)(src+4);
                float vv[8]={v0.x*msc,v0.y*msc,v0.z*msc,v0.w*msc,
                             v1.x*msc,v1.y*msc,v1.z*msc,v1.w*msc};
                ushort hh[8], ll[8];
                #pragma unroll
                for(int j=0;j<8;++j){ hh[j]=bf16_hi(vv[j]); ll[j]=bf16_hi(vv[j]-bf16_tof(hh[j])); }
                sreg[t]=*(uint4*)hh; sreg[t+4]=*(uint4*)ll;
            } else {
                int kq= ok ? qidx[b*49 + ty*IW + tx] : 0;
                const ushort* src=bookbf + (size_t)kq*512 + ic0 + slot*8;
                sreg[t]= ok ? *(const uint4*)src : z4;
            }
        }
    };

    auto stage_write=[&](){
        #pragma unroll
        for(int t=0;t<SREGS;++t){
            int idx=tid+t*256;
            int plane=idx>>10, rem=idx&1023;
            int row=rem>>3, slot=rem&7;
            int boff=plane*(BM*RB) + row*RB + ((slot^(row&7))<<4);
            *(uint4*)(sb+boff)=sreg[t];
        }
    };

    stage_load(0);
    for(int c=0;c<NCH;++c){
        __syncthreads();                // prior MFMAs done reading LDS
        stage_write();
        __syncthreads();
        if(c+1<NCH) stage_load(c+1);    // issue next-chunk loads early
        const int kk=c/ICN, ic0=(c-(c/ICN)*ICN)*64;
        #pragma unroll
        for(int ks=0;ks<2;++ks){
            short8v ah[MT]; short8v al[SPLIT?MT:1];
            #pragma unroll
            for(int m=0;m<MT;++m){
                int rl=wr*WROWS + m*16 + l15;
                int boff=rl*RB + ((((ks<<2)|lq)^l7)<<4);
                ah[m]=*(const short8v*)(sb+boff);
                if constexpr(SPLIT) al[m]=*(const short8v*)(sb+BM*RB+boff);
            }
            #pragma unroll
            for(int n=0;n<NT;++n){
                int col=n0g + n*16 + l15;
                size_t widx=((size_t)kk*OC+col)*IC + ic0 + ks*32 + lq*8;
                short8v bh=*(const short8v*)(wt_hi+widx);
                if constexpr(SPLIT){
                    short8v bl=*(const short8v*)(wt_lo+widx);
                    #pragma unroll
                    for(int m=0;m<MT;++m){
                        acc[m][n]=__builtin_amdgcn_mfma_f32_16x16x32_bf16(ah[m],bh,acc[m][n],0,0,0);
                        acc[m][n]=__builtin_amdgcn_mfma_f32_16x16x32_bf16(ah[m],bl,acc[m][n],0,0,0);
                        acc[m][n]=__builtin_amdgcn_mfma_f32_16x16x32_bf16(al[m],bh,acc[m][n],0,0,0);
                    }
                } else {
                    #pragma unroll
                    for(int m=0;m<MT;++m)
                        acc[m][n]=__builtin_amdgcn_mfma_f32_16x16x32_bf16(ah[m],bh,acc[m][n],0,0,0);
                }
            }
        }
    }

    const float rs=(float)(1.0/sqrt(1.0+1e-3));
    #pragma unroll
    for(int n=0;n<NT;++n){
        int col=n0g + n*16 + l15;
        float bi=bias[col];
        float gsc=0.f, bt=0.f;
        if constexpr(HASBN){ gsc=gamma[col]*rs; bt=beta[col]; }
        #pragma unroll
        for(int m=0;m<MT;++m){
            #pragma unroll
            for(int j=0;j<4;++j){
                size_t g=m0g + wr*WROWS + m*16 + lq*4 + j;
                float v=acc[m][n][j]+bi;
                if constexpr(HASBN) v=fmaxf(fmaf(v,gsc,bt),0.f);
                if constexpr(OUTFMT==0){
                    out_f[g*OC+col]=v;
                } else if constexpr(OUTFMT==1){
                    ushort h=bf16_hi(v);
                    out_hi[g*OC+col]=h;
                    out_lo[g*OC+col]=bf16_hi(v-bf16_tof(h));
                } else {
                    out_hi[g*OC+col]=bf16_hi(v);
                }
            }
        }
    }
}

// ---------------------------------------------------------------------------
// prep: transpose codebook, code norms, zero accumulators + worklist count
// ---------------------------------------------------------------------------
__global__ __launch_bounds__(256)
void prep_k(const float* __restrict__ book, float* __restrict__ ubt,
            float* __restrict__ cbn, float* __restrict__ acc, int* __restrict__ cnt)
{
    for (int i = threadIdx.x; i < K * CB; i += 256) {
        int k = i >> 9, c = i & 511;
        ubt[c * 64 + k] = book[i];
    }
    if (threadIdx.x < 64) {
        const float* r = book + threadIdx.x * 512;
        float s = 0.f;
        for (int c = 0; c < 512; ++c) s = fmaf(r[c], r[c], s);
        cbn[threadIdx.x] = s;
    }
    if (threadIdx.x < 2) acc[threadIdx.x] = 0.f;
    if (threadIdx.x == 0) *cnt = 0;
}

// ---------------------------------------------------------------------------
// NN search (f32): wave per 4 rows, lane = code. best + runner-up;
// gap <= MARGIN -> worklist for f64 re-verification. loss2 accumulated.
// ---------------------------------------------------------------------------
__global__ __launch_bounds__(256)
void nn_k(const float* __restrict__ xenc, const float* __restrict__ ubt,
          const float* __restrict__ cbn, int* __restrict__ qidx,
          float* __restrict__ acc, int* __restrict__ cnt, int* __restrict__ wl)
{
    const int lane = threadIdx.x & 63;
    const int wave = threadIdx.x >> 6;
    const int wid  = blockIdx.x * 4 + wave;
    const int row0 = wid * 4;
    const float* x0 = xenc + (size_t)row0 * 512;

    float dot[4] = {0.f,0.f,0.f,0.f};
    float xn[4]  = {0.f,0.f,0.f,0.f};
    for (int c = 0; c < 512; ++c) {
        float ub = ubt[c * 64 + lane];
        float a0 = x0[c], a1 = x0[512+c], a2 = x0[1024+c], a3 = x0[1536+c];
        dot[0] = fmaf(a0, ub, dot[0]);  xn[0] = fmaf(a0, a0, xn[0]);
        dot[1] = fmaf(a1, ub, dot[1]);  xn[1] = fmaf(a1, a1, xn[1]);
        dot[2] = fmaf(a2, ub, dot[2]);  xn[2] = fmaf(a2, a2, xn[2]);
        dot[3] = fmaf(a3, ub, dot[3]);  xn[3] = fmaf(a3, a3, xn[3]);
    }

    float l2sum = 0.f;
    #pragma unroll
    for (int j = 0; j < 4; ++j) {
        float d1 = cbn[lane] - 2.f * dot[j];
        int   k1 = lane;
        float d2 = 3.4e38f;
        #pragma unroll
        for (int off = 32; off > 0; off >>= 1) {
            float od1 = __shfl_xor(d1, off);
            int   ok1 = __shfl_xor(k1, off);
            float od2 = __shfl_xor(d2, off);
            if (od1 < d1 || (od1 == d1 && ok1 < k1)) {
                d2 = fminf(d1, od2); d1 = od1; k1 = ok1;
            } else {
                d2 = fminf(d2, od1);
            }
        }
        if (lane == 0) {
            qidx[row0 + j] = k1;
            if (d2 - d1 <= MARGIN) { int t = atomicAdd(cnt, 1); wl[t] = row0 + j; }
            l2sum += d1 + xn[j];
        }
    }
    if (lane == 0) atomicAdd(acc + 1, l2sum);
}

// ---------------------------------------------------------------------------
// f64 re-verification of flagged rows (full receptive field from scratch).
// ---------------------------------------------------------------------------
__global__ __launch_bounds__(256)
void recompute_k(const int* __restrict__ wl, const int* __restrict__ cnt,
                 const int* __restrict__ ids, const int* __restrict__ masks,
                 const float* __restrict__ table, const float* __restrict__ book,
                 const float* __restrict__ e_w1, const float* __restrict__ e_b1,
                 const float* __restrict__ e_g1, const float* __restrict__ e_be1,
                 const float* __restrict__ e_w2, const float* __restrict__ e_b2,
                 const float* __restrict__ e_g2, const float* __restrict__ e_be2,
                 const float* __restrict__ e_w3, const float* __restrict__ e_b3,
                 int* __restrict__ qidx)
{
    __shared__ double s_h[16*64];
    __shared__ double s_a1[9*128];
    __shared__ double s_a2[4*256];
    __shared__ double s_x[512];
    __shared__ double s_d[256];

    const int tid = threadIdx.x;
    const double rs = 1.0 / sqrt(1.0 + 1e-3);
    const int n = *cnt;

    for (int wi = blockIdx.x; wi < n; wi += gridDim.x) {
        const int row = wl[wi];
        const int b = row / 49, p = row % 49;
        const int py = p / 7, px = p % 7;

        for (int i = tid; i < 16*64; i += 256) {
            int cell = i >> 6, d = i & 63;
            int l = (py + (cell >> 2)) * 10 + (px + (cell & 3));
            int id = ids[b*100 + l];
            double m = (masks[b*100 + l] >= 1) ? 1.0 : 0.0;
            s_h[i] = (double)table[(size_t)id*64 + d] * m;
        }
        __syncthreads();

        for (int i = tid; i < 9*128; i += 256) {
            int cell = i >> 7, oc = i & 127;
            int ry = cell / 3, rx = cell % 3;
            double s = 0.0;
            #pragma unroll
            for (int kk = 0; kk < 4; ++kk) {
                int icell = (ry + (kk>>1))*4 + (rx + (kk&1));
                const double* hh = s_h + icell*64;
                const float* ww = e_w1 + (kk*64)*128 + oc;
                for (int ic = 0; ic < 64; ++ic)
                    s = fma(hh[ic], (double)ww[ic*128], s);
            }
            s += (double)e_b1[oc];
            s = s * ((double)e_g1[oc] * rs) + (double)e_be1[oc];
            s_a1[i] = s > 0.0 ? s : 0.0;
        }
        __syncthreads();

        for (int i = tid; i < 4*256; i += 256) {
            int cell = i >> 8, oc = i & 255;
            int qy = cell >> 1, qx = cell & 1;
            double s = 0.0;
            #pragma unroll
            for (int kk = 0; kk < 4; ++kk) {
                int icell = (qy + (kk>>1))*3 + (qx + (kk&1));
                const double* aa = s_a1 + icell*128;
                const float* ww = e_w2 + (kk*128)*256 + oc;
                for (int ic = 0; ic < 128; ++ic)
                    s = fma(aa[ic], (double)ww[ic*256], s);
            }
            s += (double)e_b2[oc];
            s = s * ((double)e_g2[oc] * rs) + (double)e_be2[oc];
            s_a2[i] = s > 0.0 ? s : 0.0;
        }
        __syncthreads();

        for (int i = tid; i < 512; i += 256) {
            double s = 0.0;
            #pragma unroll
            for (int kk = 0; kk < 4; ++kk) {
                const double* aa = s_a2 + kk*256;
                const float* ww = e_w3 + (kk*256)*512 + i;
                for (int ic = 0; ic < 256; ++ic)
                    s = fma(aa[ic], (double)ww[ic*512], s);
            }
            s_x[i] = s + (double)e_b3[i];
        }
        __syncthreads();

        {
            int k = tid & 63, seg = tid >> 6;
            const float* cr = book + k*512 + seg*128;
            const double* xr = s_x + seg*128;
            double s = 0.0;
            for (int c = 0; c < 128; ++c) {
                double dd = xr[c] - (double)cr[c];
                s = fma(dd, dd, s);
            }
            s_d[seg*64 + k] = s;
        }
        __syncthreads();

        if (tid < 64) {
            double dv = s_d[tid] + s_d[64+tid] + s_d[128+tid] + s_d[192+tid];
            int kk2 = tid;
            #pragma unroll
            for (int off = 32; off > 0; off >>= 1) {
                double od = __shfl_xor(dv, off);
                int    ok = __shfl_xor(kk2, off);
                if (od < dv || (od == dv && ok < kk2)) { dv = od; kk2 = ok; }
            }
            if (tid == 0) qidx[row] = kk2;
        }
        __syncthreads();
    }
}

// ---------------------------------------------------------------------------
// finalize: loss1 = sum (hist - vq_x)^2, vq_mean
// ---------------------------------------------------------------------------
__global__ __launch_bounds__(256)
void finalize_k(const float* __restrict__ vqx, const int* __restrict__ ids,
                const int* __restrict__ masks, const float* __restrict__ table,
                float* __restrict__ out_mean, float* __restrict__ acc)
{
    const int b = blockIdx.x;
    const int tid = threadIdx.x;
    const float* vb = vqx + (size_t)b * 6400;

    float part = 0.f;
    for (int i = tid; i < 6400; i += 256) {
        int l = i >> 6, d = i & 63;
        int id = ids[b * L + l];
        float m = (masks[b * L + l] >= 1) ? 1.f : 0.f;
        float h = table[(size_t)id * 64 + d] * m;
        float diff = h - vb[i];
        part = fmaf(diff, diff, part);
    }
    __shared__ float s_red[4];
    #pragma unroll
    for (int off = 32; off > 0; off >>= 1) part += __shfl_down(part, off);
    if ((tid & 63) == 0) s_red[tid >> 6] = part;
    __syncthreads();
    if (tid == 0) atomicAdd(acc + 0, s_red[0] + s_red[1] + s_red[2] + s_red[3]);

    if (tid < 64) {
        float msum = 0.f;
        for (int l = 0; l < L; ++l) msum += (masks[b * L + l] >= 1) ? 1.f : 0.f;
        float s = 0.f;
        for (int l = 0; l < L; ++l) s += vb[l * 64 + tid];
        out_mean[b * 64 + tid] = s / msum;
    }
}

__global__ void loss_k(const float* __restrict__ acc, float* __restrict__ out_loss)
{
    float l1 = acc[0] / 13107200.f;
    float l2 = acc[1] / 51380224.f;
    out_loss[0] = l1 + l2 + 0.25f * l2;
}

// ---------------------------------------------------------------------------
extern "C" void kernel_launch(void* const* d_in, const int* in_sizes, int n_in,
                              void* d_out, int out_size, void* d_ws, size_t ws_size,
                              hipStream_t stream)
{
    const int*   ids   = (const int*)d_in[0];
    const int*   masks = (const int*)d_in[1];
    const float* table = (const float*)d_in[2];
    const float* book  = (const float*)d_in[3];
    const float* e_w1  = (const float*)d_in[4];
    const float* e_b1  = (const float*)d_in[5];
    const float* e_g1  = (const float*)d_in[6];
    const float* e_be1 = (const float*)d_in[7];
    const float* e_w2  = (const float*)d_in[8];
    const float* e_b2  = (const float*)d_in[9];
    const float* e_g2  = (const float*)d_in[10];
    const float* e_be2 = (const float*)d_in[11];
    const float* e_w3  = (const float*)d_in[12];
    const float* e_b3  = (const float*)d_in[13];
    const float* d_w1  = (const float*)d_in[14];
    const float* d_b1  = (const float*)d_in[15];
    const float* d_g1  = (const float*)d_in[16];
    const float* d_be1 = (const float*)d_in[17];
    const float* d_w2  = (const float*)d_in[18];
    const float* d_b2  = (const float*)d_in[19];
    const float* d_g2  = (const float*)d_in[20];
    const float* d_be2 = (const float*)d_in[21];
    const float* d_w3  = (const float*)d_in[22];
    const float* d_b3  = (const float*)d_in[23];

    float*  ws  = (float*)d_ws;
    ushort* A1H = (ushort*)(ws + A1H_OFF);
    ushort* A1L = (ushort*)(ws + A1L_OFF);
    ushort* A2H = (ushort*)(ws + A2H_OFF);
    ushort* A2L = (ushort*)(ws + A2L_OFF);
    float*  XE  = ws + XE_OFF;
    ushort* G1  = (ushort*)(ws + G1_OFF);
    ushort* G2  = (ushort*)(ws + G2_OFF);
    int*    IDX = (int*)(ws + IDX_OFF);
    float*  UBT = ws + UBT_OFF;
    float*  CBN = ws + CBN_OFF;
    int*    CNT = (int*)(ws + CNT_OFF);
    float*  ACC = ws + ACC_OFF;
    int*    WL  = (int*)(ws + WL_OFF);
    ushort* WB  = (ushort*)(ws + WB_OFF);

    float* out_mean = (float*)d_out;
    float* out_vqx  = (float*)d_out + (size_t)B * 64;
    float* out_loss = (float*)d_out + (size_t)B * 64 + (size_t)B * L * 64;

    prep_k<<<1, 256, 0, stream>>>(book, UBT, CBN, ACC, CNT);
    wprep_k<<<512, 256, 0, stream>>>(e_w1, e_w2, e_w3, d_w1, d_w2, d_w3, book, WB);

    // encoder (split-bf16 MFMA im2col GEMMs)
    gconv_k<10,10, 64,128,0,1,true ,true ,128,2,2,1><<<dim3(1296,1),256,0,stream>>>(
        nullptr,nullptr, ids,masks,table, nullptr,nullptr,
        WB+EW1H, WB+EW1L, e_b1, e_g1, e_be1, nullptr, A1H, A1L);
    gconv_k< 9, 9,128,256,0,0,true ,true ,128,2,2,1><<<dim3(1024,2),256,0,stream>>>(
        A1H, A1L, nullptr,nullptr,nullptr, nullptr,nullptr,
        WB+EW2H, WB+EW2L, e_b2, e_g2, e_be2, nullptr, A2H, A2L);
    gconv_k< 8, 8,256,512,0,0,false,true ,128,2,2,0><<<dim3(784,4),256,0,stream>>>(
        A2H, A2L, nullptr,nullptr,nullptr, nullptr,nullptr,
        WB+EW3H, WB+EW3L, e_b3, nullptr, nullptr, XE, nullptr, nullptr);

    // codebook NN (f32 + margin flag) then f64 re-verify of flagged rows
    nn_k<<<6272, 256, 0, stream>>>(XE, UBT, CBN, IDX, ACC, CNT, WL);
    recompute_k<<<512, 256, 0, stream>>>(WL, CNT, ids, masks, table, book,
                                         e_w1, e_b1, e_g1, e_be1,
                                         e_w2, e_b2, e_g2, e_be2,
                                         e_w3, e_b3, IDX);

    // decoder (plain bf16 MFMA; conv_transpose == conv pad=1, unflipped)
    gconv_k< 7, 7,512,256,1,2,true ,false,128,2,2,2><<<dim3(1024,2),256,0,stream>>>(
        nullptr,nullptr, nullptr,nullptr,nullptr, IDX, WB+BKB,
        WB+DW1H, nullptr, d_b1, d_g1, d_be1, nullptr, G1, nullptr);
    gconv_k< 8, 8,256,128,1,0,true ,false,128,2,2,2><<<dim3(1296,1),256,0,stream>>>(
        G1, nullptr, nullptr,nullptr,nullptr, nullptr,nullptr,
        WB+DW2H, nullptr, d_b2, d_g2, d_be2, nullptr, G2, nullptr);
    gconv_k< 9, 9,128, 64,1,0,false,false, 64,4,1,0><<<dim3(1600,1),256,0,stream>>>(
        G2, nullptr, nullptr,nullptr,nullptr, nullptr,nullptr,
        WB+DW3H, nullptr, d_b3, nullptr, nullptr, out_vqx, nullptr, nullptr);

    // vq_mean + loss1, then scalar loss
    finalize_k<<<B, 256, 0, stream>>>(out_vqx, ids, masks, table, out_mean, ACC);
    loss_k<<<1, 1, 0, stream>>>(ACC, out_loss);
}

// Round 6
// 2116.468 us; speedup vs baseline: 1.4361x; 1.4361x over previous
//
#include <hip/hip_runtime.h>
#include <hip/hip_bf16.h>
#include <cstdint>
#include <cstddef>

// ---------------------------------------------------------------------------
// VQ-VAE forward (B=2048, L=100, D=64, K=64, CB=512) — per-sample MFMA v2.
// Block = (sample, oc-slice). Input tile staged ONCE in LDS (bf16 hi[+lo]),
// all 4 taps consumed from LDS (im2col-from-LDS). Weights pre-transposed
// [kk][oc][ic] bf16 and streamed from L2 (lockstep across blocks).
// Encoder: split-bf16 (3 MFMAs) ~f32 accuracy; decoder: plain bf16.
// Argmin exactness: margin 0.1 -> f64 full recompute of flagged rows.
// Encoder activations: packed u32 (bf16 hi|lo). Decoder intermediates: f32.
// ---------------------------------------------------------------------------

typedef __attribute__((ext_vector_type(8))) short short8v;   // 8 bf16
typedef __attribute__((ext_vector_type(4))) float f32x4;

constexpr int B  = 2048;
constexpr int L  = 100;
constexpr int K  = 64;
constexpr int CB = 512;
#define MARGIN 0.1f

// ---- workspace layout (float-sized units) ----
// R0: A1P u32[21233664] -> XE f32[51380224] -> G2 f32[21233664]
// R1: A2P u32[33554432] -> G1 f32[33554432]
constexpr size_t R0_OFF  = 0;
constexpr size_t R1_OFF  = 51380224;
constexpr size_t IDX_OFF = 84934656;   // 2048*49 ints
constexpr size_t UBT_OFF = 85035008;   // 512*64 f32 transposed codebook
constexpr size_t CBN_OFF = 85067776;   // 64 norms
constexpr size_t CNT_OFF = 85067840;
constexpr size_t ACC_OFF = 85067856;
constexpr size_t WL_OFF  = 85067872;   // 100352 ints
constexpr size_t WB_OFF  = 85168224;   // bf16 weights (ushort units below)

// bf16 weight sub-offsets (ushort units), layout [4][OC][IC]
constexpr size_t EW1H=0,       EW1L=32768;
constexpr size_t EW2H=65536,   EW2L=196608;
constexpr size_t EW3H=327680,  EW3L=851968;
constexpr size_t DW1H=1376256, DW2H=1900544, DW3H=2031616;
constexpr size_t BKB =2064384;  // book bf16 [64][512]

__device__ inline ushort bf16_hi(float f){ __hip_bfloat16 h=__float2bfloat16(f); return *(ushort*)&h; }
__device__ inline float  bf16_tof(ushort u){ __hip_bfloat16 h; *(ushort*)&h=u; return __bfloat162float(h); }

// ---------------------------------------------------------------------------
// weight prep: w[2,2,IC,OC] f32 -> Wt[kk][oc][ic] bf16 hi (+lo for encoder);
// book -> bf16.
// ---------------------------------------------------------------------------
__device__ void wtrans(const float* __restrict__ w, int IC, int OC,
                       ushort* __restrict__ hi, ushort* __restrict__ lo,
                       int gid, int gsz)
{
    int tot = 4*IC*OC;
    for (int i = gid; i < tot; i += gsz) {
        int kk = i/(IC*OC), r = i - kk*(IC*OC), ic = r/OC, oc = r - ic*OC;
        float v = w[i];
        ushort h = bf16_hi(v);
        size_t dst = ((size_t)kk*OC + oc)*IC + ic;
        hi[dst] = h;
        if (lo) lo[dst] = bf16_hi(v - bf16_tof(h));
    }
}

__global__ __launch_bounds__(256)
void wprep_k(const float* e1, const float* e2, const float* e3,
             const float* d1, const float* d2, const float* d3,
             const float* book, ushort* wb)
{
    int gid = blockIdx.x*256 + threadIdx.x, gsz = gridDim.x*256;
    wtrans(e1,  64, 128, wb+EW1H, wb+EW1L, gid, gsz);
    wtrans(e2, 128, 256, wb+EW2H, wb+EW2L, gid, gsz);
    wtrans(e3, 256, 512, wb+EW3H, wb+EW3L, gid, gsz);
    wtrans(d1, 512, 256, wb+DW1H, nullptr, gid, gsz);
    wtrans(d2, 256, 128, wb+DW2H, nullptr, gid, gsz);
    wtrans(d3, 128,  64, wb+DW3H, nullptr, gid, gsz);
    for (int i = gid; i < 64*512; i += gsz) wb[BKB+i] = bf16_hi(book[i]);
}

// ---------------------------------------------------------------------------
// Per-sample MFMA conv. Block = (sample b, oc-slice s). 4 waves split the
// slice's OC. LDS holds the sample's ICC-channel chunk for ALL rows (+zero
// row), XOR-swizzled; all 4 taps read from LDS.
// A-frag: lane&15=pos-row, k=(lane>>4)*8+j (ds_read_b128).
// B-frag: lane&15=oc col, 16B global load from Wt[kk][oc][ic].
// C: col=lane&15, row=(lane>>4)*4+j.
// MODE 0: f32 in; 1: table gather+mask; 2: bookbf gather; 3: packed u32 in.
// OUTFMT 0: f32; 1: packed u32 (hi|lo).
// ---------------------------------------------------------------------------
template<int IH,int IW,int IC,int OC,int PAD,int MODE,bool HASBN,bool SPLIT,
         int OCS,int ICC,int MT,int OUTFMT>
__global__ __launch_bounds__(256)
void sconv_k(const float* __restrict__ in_f, const uint* __restrict__ in_pk,
             const int* __restrict__ ids, const int* __restrict__ masks,
             const float* __restrict__ table,
             const int* __restrict__ qidx, const ushort* __restrict__ bookbf,
             const ushort* __restrict__ wt_hi, const ushort* __restrict__ wt_lo,
             const float* __restrict__ bias, const float* __restrict__ gamma,
             const float* __restrict__ beta,
             float* __restrict__ out_f, uint* __restrict__ out_pk)
{
    constexpr int OH=IH+2*PAD-1, OW=IW+2*PAD-1, NPOS=OH*OW, IHW=IH*IW;
    constexpr int OCB=OC/OCS, NPW=OCB/4, NT=NPW/16;
    constexpr int NCH=IC/ICC, KS=ICC/32;
    constexpr int PL=SPLIT?2:1;
    constexpr int AROWS=IHW+1, RB=ICC*2;
    constexpr int C8=ICC/8;

    __shared__ ushort s_a[PL*AROWS*ICC];
    char* sb=(char*)s_a;

    const int bx=blockIdx.x, b=bx/OCS, sl=bx%OCS;
    const int tid=threadIdx.x, lane=tid&63, wv=tid>>6;
    const int l15=lane&15, lq=lane>>4;
    const int n0=sl*OCB + wv*NPW;

    // per-tap LDS row tables (tap geometry is chunk-invariant)
    int arow[4][MT];
    #pragma unroll
    for(int kk=0;kk<4;++kk){
        const int ky=kk>>1, kx=kk&1;
        #pragma unroll
        for(int m=0;m<MT;++m){
            int p=m*16+l15;
            int py=p/OW, px=p-py*OW;
            int ty=py+ky-PAD, tx=px+kx-PAD;
            bool ok=(p<NPOS)&&((unsigned)ty<(unsigned)IH)&&((unsigned)tx<(unsigned)IW);
            arow[kk][m]= ok ? ty*IW+tx : IHW;
        }
    }

    f32x4 acc[MT][NT];
    #pragma unroll
    for(int m=0;m<MT;++m)
        #pragma unroll
        for(int n=0;n<NT;++n) acc[m][n]=(f32x4)0.0f;

    for(int ch=0; ch<NCH; ++ch){
        const int ic0=ch*ICC;
        if(ch) __syncthreads();
        // zero row
        for(int g2=tid; g2<PL*C8; g2+=256){
            int pl=g2/C8, g=g2-pl*C8;
            int off=pl*(AROWS*RB) + IHW*RB + ((g*16)^((IHW&7)<<4));
            *(uint4*)(sb+off)=make_uint4(0,0,0,0);
        }
        // stage rows
        for(int i=tid; i<IHW*C8; i+=256){
            int row=i/C8, g=i-row*C8;
            int boff=row*RB + ((g*16)^((row&7)<<4));
            if constexpr(MODE==3){
                const uint* src=in_pk + ((size_t)b*IHW+row)*IC + ic0 + g*8;
                uint4 u0=*(const uint4*)src, u1=*(const uint4*)(src+4);
                uint uu[8]={u0.x,u0.y,u0.z,u0.w,u1.x,u1.y,u1.z,u1.w};
                ushort hh[8], ll[8];
                #pragma unroll
                for(int j=0;j<8;++j){ hh[j]=(ushort)(uu[j]&0xffffu); ll[j]=(ushort)(uu[j]>>16); }
                *(uint4*)(sb+boff)=*(uint4*)hh;
                *(uint4*)(sb+AROWS*RB+boff)=*(uint4*)ll;
            } else if constexpr(MODE==0){
                const float* src=in_f + ((size_t)b*IHW+row)*IC + ic0 + g*8;
                float4 v0=*(const float4*)src, v1=*(const float4*)(src+4);
                float vv[8]={v0.x,v0.y,v0.z,v0.w,v1.x,v1.y,v1.z,v1.w};
                ushort hh[8];
                #pragma unroll
                for(int j=0;j<8;++j) hh[j]=bf16_hi(vv[j]);
                *(uint4*)(sb+boff)=*(uint4*)hh;
            } else if constexpr(MODE==1){
                int id=ids[b*L+row];
                float msc=(masks[b*L+row]>=1)?1.f:0.f;
                const float* src=table + (size_t)id*64 + g*8;   // ICC==IC==64
                float4 v0=*(const float4*)src, v1=*(const float4*)(src+4);
                float vv[8]={v0.x*msc,v0.y*msc,v0.z*msc,v0.w*msc,
                             v1.x*msc,v1.y*msc,v1.z*msc,v1.w*msc};
                ushort hh[8], ll[8];
                #pragma unroll
                for(int j=0;j<8;++j){ hh[j]=bf16_hi(vv[j]); ll[j]=bf16_hi(vv[j]-bf16_tof(hh[j])); }
                *(uint4*)(sb+boff)=*(uint4*)hh;
                *(uint4*)(sb+AROWS*RB+boff)=*(uint4*)ll;
            } else { // MODE 2
                int kq=qidx[b*49+row];
                const ushort* src=bookbf + (size_t)kq*512 + ic0 + g*8;
                *(uint4*)(sb+boff)=*(const uint4*)src;
            }
        }
        __syncthreads();

        // fully-unrolled K body: compiler hoists independent B global loads
        #pragma unroll
        for(int kk=0;kk<4;++kk){
            #pragma unroll
            for(int ks=0;ks<KS;++ks){
                short8v ah[MT]; short8v al[SPLIT?MT:1];
                #pragma unroll
                for(int m=0;m<MT;++m){
                    int off=arow[kk][m]*RB + (((ks*4+lq)*16) ^ ((arow[kk][m]&7)<<4));
                    ah[m]=*(const short8v*)(sb+off);
                    if constexpr(SPLIT) al[m]=*(const short8v*)(sb+AROWS*RB+off);
                }
                #pragma unroll
                for(int n=0;n<NT;++n){
                    int col=n0 + n*16 + l15;
                    size_t widx=((size_t)kk*OC+col)*IC + ic0 + ks*32 + lq*8;
                    short8v bh=*(const short8v*)(wt_hi+widx);
                    if constexpr(SPLIT){
                        short8v bl=*(const short8v*)(wt_lo+widx);
                        #pragma unroll
                        for(int m=0;m<MT;++m){
                            acc[m][n]=__builtin_amdgcn_mfma_f32_16x16x32_bf16(ah[m],bh,acc[m][n],0,0,0);
                            acc[m][n]=__builtin_amdgcn_mfma_f32_16x16x32_bf16(ah[m],bl,acc[m][n],0,0,0);
                            acc[m][n]=__builtin_amdgcn_mfma_f32_16x16x32_bf16(al[m],bh,acc[m][n],0,0,0);
                        }
                    } else {
                        #pragma unroll
                        for(int m=0;m<MT;++m)
                            acc[m][n]=__builtin_amdgcn_mfma_f32_16x16x32_bf16(ah[m],bh,acc[m][n],0,0,0);
                    }
                }
            }
        }
    }

    const float rs=(float)(1.0/sqrt(1.0+1e-3));
    #pragma unroll
    for(int n=0;n<NT;++n){
        int col=n0 + n*16 + l15;
        float bi=bias[col];
        float gsc=0.f, bt=0.f;
        if constexpr(HASBN){ gsc=gamma[col]*rs; bt=beta[col]; }
        #pragma unroll
        for(int m=0;m<MT;++m){
            #pragma unroll
            for(int j=0;j<4;++j){
                int p=m*16+lq*4+j;
                if(p<NPOS){
                    float v=acc[m][n][j]+bi;
                    if constexpr(HASBN) v=fmaxf(fmaf(v,gsc,bt),0.f);
                    size_t g=(size_t)b*NPOS+p;
                    if constexpr(OUTFMT==0){
                        out_f[g*OC+col]=v;
                    } else {
                        ushort h=bf16_hi(v);
                        ushort lo=bf16_hi(v-bf16_tof(h));
                        out_pk[g*OC+col]=(uint)h | ((uint)lo<<16);
                    }
                }
            }
        }
    }
}

// ---------------------------------------------------------------------------
// prep: transpose codebook, code norms, zero accumulators + worklist count
// ---------------------------------------------------------------------------
__global__ __launch_bounds__(256)
void prep_k(const float* __restrict__ book, float* __restrict__ ubt,
            float* __restrict__ cbn, float* __restrict__ acc, int* __restrict__ cnt)
{
    for (int i = threadIdx.x; i < K * CB; i += 256) {
        int k = i >> 9, c = i & 511;
        ubt[c * 64 + k] = book[i];
    }
    if (threadIdx.x < 64) {
        const float* r = book + threadIdx.x * 512;
        float s = 0.f;
        for (int c = 0; c < 512; ++c) s = fmaf(r[c], r[c], s);
        cbn[threadIdx.x] = s;
    }
    if (threadIdx.x < 2) acc[threadIdx.x] = 0.f;
    if (threadIdx.x == 0) *cnt = 0;
}

// ---------------------------------------------------------------------------
// NN search (f32): wave per 4 rows, lane = code. best + runner-up;
// gap <= MARGIN -> worklist for f64 re-verification. loss2 accumulated.
// ---------------------------------------------------------------------------
__global__ __launch_bounds__(256)
void nn_k(const float* __restrict__ xenc, const float* __restrict__ ubt,
          const float* __restrict__ cbn, int* __restrict__ qidx,
          float* __restrict__ acc, int* __restrict__ cnt, int* __restrict__ wl)
{
    const int lane = threadIdx.x & 63;
    const int wave = threadIdx.x >> 6;
    const int wid  = blockIdx.x * 4 + wave;
    const int row0 = wid * 4;
    const float* x0 = xenc + (size_t)row0 * 512;

    float dot[4] = {0.f,0.f,0.f,0.f};
    float xn[4]  = {0.f,0.f,0.f,0.f};
    for (int c = 0; c < 512; ++c) {
        float ub = ubt[c * 64 + lane];
        float a0 = x0[c], a1 = x0[512+c], a2 = x0[1024+c], a3 = x0[1536+c];
        dot[0] = fmaf(a0, ub, dot[0]);  xn[0] = fmaf(a0, a0, xn[0]);
        dot[1] = fmaf(a1, ub, dot[1]);  xn[1] = fmaf(a1, a1, xn[1]);
        dot[2] = fmaf(a2, ub, dot[2]);  xn[2] = fmaf(a2, a2, xn[2]);
        dot[3] = fmaf(a3, ub, dot[3]);  xn[3] = fmaf(a3, a3, xn[3]);
    }

    float l2sum = 0.f;
    #pragma unroll
    for (int j = 0; j < 4; ++j) {
        float d1 = cbn[lane] - 2.f * dot[j];
        int   k1 = lane;
        float d2 = 3.4e38f;
        #pragma unroll
        for (int off = 32; off > 0; off >>= 1) {
            float od1 = __shfl_xor(d1, off);
            int   ok1 = __shfl_xor(k1, off);
            float od2 = __shfl_xor(d2, off);
            if (od1 < d1 || (od1 == d1 && ok1 < k1)) {
                d2 = fminf(d1, od2); d1 = od1; k1 = ok1;
            } else {
                d2 = fminf(d2, od1);
            }
        }
        if (lane == 0) {
            qidx[row0 + j] = k1;
            if (d2 - d1 <= MARGIN) { int t = atomicAdd(cnt, 1); wl[t] = row0 + j; }
            l2sum += d1 + xn[j];
        }
    }
    if (lane == 0) atomicAdd(acc + 1, l2sum);
}

// ---------------------------------------------------------------------------
// f64 re-verification of flagged rows (full receptive field from scratch).
// ---------------------------------------------------------------------------
__global__ __launch_bounds__(256)
void recompute_k(const int* __restrict__ wl, const int* __restrict__ cnt,
                 const int* __restrict__ ids, const int* __restrict__ masks,
                 const float* __restrict__ table, const float* __restrict__ book,
                 const float* __restrict__ e_w1, const float* __restrict__ e_b1,
                 const float* __restrict__ e_g1, const float* __restrict__ e_be1,
                 const float* __restrict__ e_w2, const float* __restrict__ e_b2,
                 const float* __restrict__ e_g2, const float* __restrict__ e_be2,
                 const float* __restrict__ e_w3, const float* __restrict__ e_b3,
                 int* __restrict__ qidx)
{
    __shared__ double s_h[16*64];
    __shared__ double s_a1[9*128];
    __shared__ double s_a2[4*256];
    __shared__ double s_x[512];
    __shared__ double s_d[256];

    const int tid = threadIdx.x;
    const double rs = 1.0 / sqrt(1.0 + 1e-3);
    const int n = *cnt;

    for (int wi = blockIdx.x; wi < n; wi += gridDim.x) {
        const int row = wl[wi];
        const int b = row / 49, p = row % 49;
        const int py = p / 7, px = p % 7;

        for (int i = tid; i < 16*64; i += 256) {
            int cell = i >> 6, d = i & 63;
            int l = (py + (cell >> 2)) * 10 + (px + (cell & 3));
            int id = ids[b*100 + l];
            double m = (masks[b*100 + l] >= 1) ? 1.0 : 0.0;
            s_h[i] = (double)table[(size_t)id*64 + d] * m;
        }
        __syncthreads();

        for (int i = tid; i < 9*128; i += 256) {
            int cell = i >> 7, oc = i & 127;
            int ry = cell / 3, rx = cell % 3;
            double s = 0.0;
            #pragma unroll
            for (int kk = 0; kk < 4; ++kk) {
                int icell = (ry + (kk>>1))*4 + (rx + (kk&1));
                const double* hh = s_h + icell*64;
                const float* ww = e_w1 + (kk*64)*128 + oc;
                for (int ic = 0; ic < 64; ++ic)
                    s = fma(hh[ic], (double)ww[ic*128], s);
            }
            s += (double)e_b1[oc];
            s = s * ((double)e_g1[oc] * rs) + (double)e_be1[oc];
            s_a1[i] = s > 0.0 ? s : 0.0;
        }
        __syncthreads();

        for (int i = tid; i < 4*256; i += 256) {
            int cell = i >> 8, oc = i & 255;
            int qy = cell >> 1, qx = cell & 1;
            double s = 0.0;
            #pragma unroll
            for (int kk = 0; kk < 4; ++kk) {
                int icell = (qy + (kk>>1))*3 + (qx + (kk&1));
                const double* aa = s_a1 + icell*128;
                const float* ww = e_w2 + (kk*128)*256 + oc;
                for (int ic = 0; ic < 128; ++ic)
                    s = fma(aa[ic], (double)ww[ic*256], s);
            }
            s += (double)e_b2[oc];
            s = s * ((double)e_g2[oc] * rs) + (double)e_be2[oc];
            s_a2[i] = s > 0.0 ? s : 0.0;
        }
        __syncthreads();

        for (int i = tid; i < 512; i += 256) {
            double s = 0.0;
            #pragma unroll
            for (int kk = 0; kk < 4; ++kk) {
                const double* aa = s_a2 + kk*256;
                const float* ww = e_w3 + (kk*256)*512 + i;
                for (int ic = 0; ic < 256; ++ic)
                    s = fma(aa[ic], (double)ww[ic*512], s);
            }
            s_x[i] = s + (double)e_b3[i];
        }
        __syncthreads();

        {
            int k = tid & 63, seg = tid >> 6;
            const float* cr = book + k*512 + seg*128;
            const double* xr = s_x + seg*128;
            double s = 0.0;
            for (int c = 0; c < 128; ++c) {
                double dd = xr[c] - (double)cr[c];
                s = fma(dd, dd, s);
            }
            s_d[seg*64 + k] = s;
        }
        __syncthreads();

        if (tid < 64) {
            double dv = s_d[tid] + s_d[64+tid] + s_d[128+tid] + s_d[192+tid];
            int kk2 = tid;
            #pragma unroll
            for (int off = 32; off > 0; off >>= 1) {
                double od = __shfl_xor(dv, off);
                int    ok = __shfl_xor(kk2, off);
                if (od < dv || (od == dv && ok < kk2)) { dv = od; kk2 = ok; }
            }
            if (tid == 0) qidx[row] = kk2;
        }
        __syncthreads();
    }
}

// ---------------------------------------------------------------------------
// finalize: loss1 = sum (hist - vq_x)^2, vq_mean
// ---------------------------------------------------------------------------
__global__ __launch_bounds__(256)
void finalize_k(const float* __restrict__ vqx, const int* __restrict__ ids,
                const int* __restrict__ masks, const float* __restrict__ table,
                float* __restrict__ out_mean, float* __restrict__ acc)
{
    const int b = blockIdx.x;
    const int tid = threadIdx.x;
    const float* vb = vqx + (size_t)b * 6400;

    float part = 0.f;
    for (int i = tid; i < 6400; i += 256) {
        int l = i >> 6, d = i & 63;
        int id = ids[b * L + l];
        float m = (masks[b * L + l] >= 1) ? 1.f : 0.f;
        float h = table[(size_t)id * 64 + d] * m;
        float diff = h - vb[i];
        part = fmaf(diff, diff, part);
    }
    __shared__ float s_red[4];
    #pragma unroll
    for (int off = 32; off > 0; off >>= 1) part += __shfl_down(part, off);
    if ((tid & 63) == 0) s_red[tid >> 6] = part;
    __syncthreads();
    if (tid == 0) atomicAdd(acc + 0, s_red[0] + s_red[1] + s_red[2] + s_red[3]);

    if (tid < 64) {
        float msum = 0.f;
        for (int l = 0; l < L; ++l) msum += (masks[b * L + l] >= 1) ? 1.f : 0.f;
        float s = 0.f;
        for (int l = 0; l < L; ++l) s += vb[l * 64 + tid];
        out_mean[b * 64 + tid] = s / msum;
    }
}

__global__ void loss_k(const float* __restrict__ acc, float* __restrict__ out_loss)
{
    float l1 = acc[0] / 13107200.f;
    float l2 = acc[1] / 51380224.f;
    out_loss[0] = l1 + l2 + 0.25f * l2;
}

// ---------------------------------------------------------------------------
extern "C" void kernel_launch(void* const* d_in, const int* in_sizes, int n_in,
                              void* d_out, int out_size, void* d_ws, size_t ws_size,
                              hipStream_t stream)
{
    const int*   ids   = (const int*)d_in[0];
    const int*   masks = (const int*)d_in[1];
    const float* table = (const float*)d_in[2];
    const float* book  = (const float*)d_in[3];
    const float* e_w1  = (const float*)d_in[4];
    const float* e_b1  = (const float*)d_in[5];
    const float* e_g1  = (const float*)d_in[6];
    const float* e_be1 = (const float*)d_in[7];
    const float* e_w2  = (const float*)d_in[8];
    const float* e_b2  = (const float*)d_in[9];
    const float* e_g2  = (const float*)d_in[10];
    const float* e_be2 = (const float*)d_in[11];
    const float* e_w3  = (const float*)d_in[12];
    const float* e_b3  = (const float*)d_in[13];
    const float* d_w1  = (const float*)d_in[14];
    const float* d_b1  = (const float*)d_in[15];
    const float* d_g1  = (const float*)d_in[16];
    const float* d_be1 = (const float*)d_in[17];
    const float* d_w2  = (const float*)d_in[18];
    const float* d_b2  = (const float*)d_in[19];
    const float* d_g2  = (const float*)d_in[20];
    const float* d_be2 = (const float*)d_in[21];
    const float* d_w3  = (const float*)d_in[22];
    const float* d_b3  = (const float*)d_in[23];

    float*  ws  = (float*)d_ws;
    uint*   A1P = (uint*)(ws + R0_OFF);   // [B*81*128] u32 hi|lo
    uint*   A2P = (uint*)(ws + R1_OFF);   // [B*64*256] u32 hi|lo
    float*  XE  = ws + R0_OFF;            // [B*49*512] f32
    float*  G1  = ws + R1_OFF;            // [B*64*256] f32
    float*  G2  = ws + R0_OFF;            // [B*81*128] f32
    int*    IDX = (int*)(ws + IDX_OFF);
    float*  UBT = ws + UBT_OFF;
    float*  CBN = ws + CBN_OFF;
    int*    CNT = (int*)(ws + CNT_OFF);
    float*  ACC = ws + ACC_OFF;
    int*    WL  = (int*)(ws + WL_OFF);
    ushort* WB  = (ushort*)(ws + WB_OFF);

    float* out_mean = (float*)d_out;
    float* out_vqx  = (float*)d_out + (size_t)B * 64;
    float* out_loss = (float*)d_out + (size_t)B * 64 + (size_t)B * L * 64;

    prep_k<<<1, 256, 0, stream>>>(book, UBT, CBN, ACC, CNT);
    wprep_k<<<512, 256, 0, stream>>>(e_w1, e_w2, e_w3, d_w1, d_w2, d_w3, book, WB);

    // encoder (split-bf16): conv1 gathers table; conv2/3 read packed planes
    sconv_k<10,10, 64,128,0,1,true ,true ,1, 64,6,1><<<B,   256,0,stream>>>(
        nullptr, nullptr, ids, masks, table, nullptr, nullptr,
        WB+EW1H, WB+EW1L, e_b1, e_g1, e_be1, nullptr, A1P);
    sconv_k< 9, 9,128,256,0,3,true ,true ,2,128,4,1><<<B*2, 256,0,stream>>>(
        nullptr, A1P, nullptr, nullptr, nullptr, nullptr, nullptr,
        WB+EW2H, WB+EW2L, e_b2, e_g2, e_be2, nullptr, A2P);
    sconv_k< 8, 8,256,512,0,3,false,true ,4,128,4,0><<<B*4, 256,0,stream>>>(
        nullptr, A2P, nullptr, nullptr, nullptr, nullptr, nullptr,
        WB+EW3H, WB+EW3L, e_b3, nullptr, nullptr, XE, nullptr);

    // codebook NN (f32 + margin flag) then f64 re-verify of flagged rows
    nn_k<<<6272, 256, 0, stream>>>(XE, UBT, CBN, IDX, ACC, CNT, WL);
    recompute_k<<<512, 256, 0, stream>>>(WL, CNT, ids, masks, table, book,
                                         e_w1, e_b1, e_g1, e_be1,
                                         e_w2, e_b2, e_g2, e_be2,
                                         e_w3, e_b3, IDX);

    // decoder (plain bf16; conv_transpose == conv pad=1, unflipped kernel)
    sconv_k< 7, 7,512,256,1,2,true ,false,2,128,4,0><<<B*2, 256,0,stream>>>(
        nullptr, nullptr, nullptr, nullptr, nullptr, IDX, WB+BKB,
        WB+DW1H, nullptr, d_b1, d_g1, d_be1, G1, nullptr);
    sconv_k< 8, 8,256,128,1,0,true ,false,1,128,6,0><<<B,   256,0,stream>>>(
        G1, nullptr, nullptr, nullptr, nullptr, nullptr, nullptr,
        WB+DW2H, nullptr, d_b2, d_g2, d_be2, G2, nullptr);
    sconv_k< 9, 9,128, 64,1,0,false,false,1,128,7,0><<<B,   256,0,stream>>>(
        G2, nullptr, nullptr, nullptr, nullptr, nullptr, nullptr,
        WB+DW3H, nullptr, d_b3, nullptr, nullptr, out_vqx, nullptr);

    // vq_mean + loss1, then scalar loss
    finalize_k<<<B, 256, 0, stream>>>(out_vqx, ids, masks, table, out_mean, ACC);
    loss_k<<<1, 1, 0, stream>>>(ACC, out_loss);
}

// Round 7
// 2028.970 us; speedup vs baseline: 1.4980x; 1.0431x over previous
//
#include <hip/hip_runtime.h>
#include <hip/hip_bf16.h>
#include <cstdint>
#include <cstddef>

// ---------------------------------------------------------------------------
// VQ-VAE forward (B=2048, L=100, D=64, K=64, CB=512) — per-sample MFMA v3.
// Levers this round: LDS diet (ICC=64 encoder) for occupancy, hoisted B-frags
// + transient A-frags for VGPR, T14 prefetch (next chunk's global loads issue
// before current chunk's MFMAs), XCD-aware block remap (slices of one sample
// share an L2), bf16 decoder intermediates, finalize fused into deconv3.
// Encoder: split-bf16 (3 MFMAs) ~f32 accuracy; decoder: plain bf16.
// Argmin exactness: margin 0.1 -> f64 full recompute of flagged rows.
// ---------------------------------------------------------------------------

typedef __attribute__((ext_vector_type(8))) short short8v;   // 8 bf16
typedef __attribute__((ext_vector_type(4))) float f32x4;

constexpr int B  = 2048;
constexpr int L  = 100;
constexpr int K  = 64;
constexpr int CB = 512;
#define MARGIN 0.1f

// ---- workspace layout (float-sized units) ----
// R0: A1P u32[21233664] -> XE f32[51380224] -> G2 ushort[21233664]
// R1: A2P u32[33554432] -> G1 ushort[33554432]
constexpr size_t R0_OFF  = 0;
constexpr size_t R1_OFF  = 51380224;
constexpr size_t IDX_OFF = 84934656;   // 2048*49 ints
constexpr size_t UBT_OFF = 85035008;   // 512*64 f32 transposed codebook
constexpr size_t CBN_OFF = 85067776;   // 64 norms
constexpr size_t CNT_OFF = 85067840;
constexpr size_t ACC_OFF = 85067856;
constexpr size_t WL_OFF  = 85067872;   // 100352 ints
constexpr size_t WB_OFF  = 85168224;   // bf16 weights (ushort units below)

// bf16 weight sub-offsets (ushort units), layout [4][OC][IC]
constexpr size_t EW1H=0,       EW1L=32768;
constexpr size_t EW2H=65536,   EW2L=196608;
constexpr size_t EW3H=327680,  EW3L=851968;
constexpr size_t DW1H=1376256, DW2H=1900544, DW3H=2031616;
constexpr size_t BKB =2064384;  // book bf16 [64][512]

__device__ inline ushort bf16_hi(float f){ __hip_bfloat16 h=__float2bfloat16(f); return *(ushort*)&h; }
__device__ inline float  bf16_tof(ushort u){ __hip_bfloat16 h; *(ushort*)&h=u; return __bfloat162float(h); }

// ---------------------------------------------------------------------------
// weight prep: w[2,2,IC,OC] f32 -> Wt[kk][oc][ic] bf16 hi (+lo for encoder);
// book -> bf16.
// ---------------------------------------------------------------------------
__device__ void wtrans(const float* __restrict__ w, int IC, int OC,
                       ushort* __restrict__ hi, ushort* __restrict__ lo,
                       int gid, int gsz)
{
    int tot = 4*IC*OC;
    for (int i = gid; i < tot; i += gsz) {
        int kk = i/(IC*OC), r = i - kk*(IC*OC), ic = r/OC, oc = r - ic*OC;
        float v = w[i];
        ushort h = bf16_hi(v);
        size_t dst = ((size_t)kk*OC + oc)*IC + ic;
        hi[dst] = h;
        if (lo) lo[dst] = bf16_hi(v - bf16_tof(h));
    }
}

__global__ __launch_bounds__(256)
void wprep_k(const float* e1, const float* e2, const float* e3,
             const float* d1, const float* d2, const float* d3,
             const float* book, ushort* wb)
{
    int gid = blockIdx.x*256 + threadIdx.x, gsz = gridDim.x*256;
    wtrans(e1,  64, 128, wb+EW1H, wb+EW1L, gid, gsz);
    wtrans(e2, 128, 256, wb+EW2H, wb+EW2L, gid, gsz);
    wtrans(e3, 256, 512, wb+EW3H, wb+EW3L, gid, gsz);
    wtrans(d1, 512, 256, wb+DW1H, nullptr, gid, gsz);
    wtrans(d2, 256, 128, wb+DW2H, nullptr, gid, gsz);
    wtrans(d3, 128,  64, wb+DW3H, nullptr, gid, gsz);
    for (int i = gid; i < 64*512; i += gsz) wb[BKB+i] = bf16_hi(book[i]);
}

// ---------------------------------------------------------------------------
// Per-sample MFMA conv. Block = (sample b, oc-slice sl), remapped so all
// slices of a sample land on one XCD. 4 waves split the slice's OC.
// LDS: ICC-channel chunk for all rows (+zero row), XOR-swizzled.
// T14: next chunk's global loads issue before current chunk's MFMA cluster.
// MODE 1: table gather+mask (f32->hi/lo); 2: bookbf via qidx; 3: packed u32
// hi|lo planes; 4: bf16 ushort.  OUTFMT 0: f32; 1: packed u32; 2: bf16.
// FUSE: deconv3 epilogue also computes vq_mean and accumulates loss1.
// ---------------------------------------------------------------------------
template<int IH,int IW,int IC,int OC,int PAD,int MODE,bool HASBN,bool SPLIT,
         int OCS,int ICC,int MT,int OUTFMT,bool FUSE>
__global__ __launch_bounds__(256)
void sconv_k(const uint* __restrict__ in_pk, const ushort* __restrict__ in_bf,
             const int* __restrict__ ids, const int* __restrict__ masks,
             const float* __restrict__ table,
             const int* __restrict__ qidx, const ushort* __restrict__ bookbf,
             const ushort* __restrict__ wt_hi, const ushort* __restrict__ wt_lo,
             const float* __restrict__ bias, const float* __restrict__ gamma,
             const float* __restrict__ beta,
             float* __restrict__ out_f, uint* __restrict__ out_pk,
             ushort* __restrict__ out_bf, float* __restrict__ out_mean,
             float* __restrict__ acc_g)
{
    constexpr int OH=IH+2*PAD-1, OW=IW+2*PAD-1, NPOS=OH*OW, IHW=IH*IW;
    constexpr int OCB=OC/OCS, NPW=OCB/4, NT=NPW/16;
    constexpr int NCH=IC/ICC, KS=ICC/32;
    constexpr int PL=SPLIT?2:1;
    constexpr int AROWS=IHW+1, RB=ICC*2;
    constexpr int C8=ICC/8;
    constexpr int NITEMS=IHW*C8;
    constexpr int SI=(NITEMS+255)/256;
    constexpr bool EXACT=(SI*256==NITEMS);

    __shared__ ushort s_a[PL*AROWS*ICC];
    char* sb=(char*)s_a;

    // XCD-aware remap: all OCS slices of a sample live on one XCD.
    const int v=blockIdx.x, r8=v&7, iv=v>>3;
    const int b = r8*(B/8) + iv/OCS;
    const int sl = iv - (iv/OCS)*OCS;

    const int tid=threadIdx.x, lane=tid&63, wv=tid>>6;
    const int l15=lane&15, lq=lane>>4;
    const int n0=sl*OCB + wv*NPW;

    f32x4 acc[MT][NT];
    #pragma unroll
    for(int m=0;m<MT;++m)
        #pragma unroll
        for(int n=0;n<NT;++n) acc[m][n]=(f32x4)0.0f;

    // staging registers
    uint4 r0[SI];
    uint4 r1[(MODE==1||MODE==3)?SI:1];
    float msk[(MODE==1)?SI:1];

    auto stage_load=[&](int c){
        const int ic0=c*ICC;
        #pragma unroll
        for(int t=0;t<SI;++t){
            int idx=tid+t*256;
            if(EXACT || idx<NITEMS){
                int row=idx/C8, g=idx-row*C8;
                if constexpr(MODE==1){
                    int id=ids[b*L+row];
                    msk[t]=(masks[b*L+row]>=1)?1.f:0.f;
                    const float* src=table+(size_t)id*64+g*8;      // ICC==IC==64
                    r0[t]=*(const uint4*)src;
                    r1[t]=*(const uint4*)(src+4);
                } else if constexpr(MODE==2){
                    int kq=qidx[b*49+row];
                    r0[t]=*(const uint4*)(bookbf+(size_t)kq*512+ic0+g*8);
                } else if constexpr(MODE==3){
                    const uint* src=in_pk+((size_t)b*IHW+row)*IC+ic0+g*8;
                    r0[t]=*(const uint4*)src;
                    r1[t]=*(const uint4*)(src+4);
                } else {
                    r0[t]=*(const uint4*)(in_bf+((size_t)b*IHW+row)*IC+ic0+g*8);
                }
            }
        }
    };

    auto stage_write=[&](){
        #pragma unroll
        for(int t=0;t<SI;++t){
            int idx=tid+t*256;
            if(EXACT || idx<NITEMS){
                int row=idx/C8, g=idx-row*C8;
                int boff=row*RB+((g^(row&7))<<4);
                if constexpr(MODE==1){
                    const float* f0=(const float*)&r0[t];
                    const float* f1=(const float*)&r1[t];
                    float vv[8]={f0[0]*msk[t],f0[1]*msk[t],f0[2]*msk[t],f0[3]*msk[t],
                                 f1[0]*msk[t],f1[1]*msk[t],f1[2]*msk[t],f1[3]*msk[t]};
                    ushort hh[8], ll[8];
                    #pragma unroll
                    for(int j=0;j<8;++j){ hh[j]=bf16_hi(vv[j]); ll[j]=bf16_hi(vv[j]-bf16_tof(hh[j])); }
                    *(uint4*)(sb+boff)=*(uint4*)hh;
                    *(uint4*)(sb+AROWS*RB+boff)=*(uint4*)ll;
                } else if constexpr(MODE==3){
                    const uint* u0=(const uint*)&r0[t];
                    const uint* u1=(const uint*)&r1[t];
                    ushort hh[8], ll[8];
                    #pragma unroll
                    for(int j=0;j<4;++j){ hh[j]=(ushort)(u0[j]&0xffffu); ll[j]=(ushort)(u0[j]>>16); }
                    #pragma unroll
                    for(int j=0;j<4;++j){ hh[4+j]=(ushort)(u1[j]&0xffffu); ll[4+j]=(ushort)(u1[j]>>16); }
                    *(uint4*)(sb+boff)=*(uint4*)hh;
                    *(uint4*)(sb+AROWS*RB+boff)=*(uint4*)ll;
                } else {
                    *(uint4*)(sb+boff)=r0[t];
                }
            }
        }
    };

    stage_load(0);
    // zero row (index IHW) in each plane — written once, never overwritten
    for(int z=tid; z<PL*C8; z+=256){
        int pl=z/C8, g=z-pl*C8;
        *(uint4*)(sb + pl*(AROWS*RB) + IHW*RB + (g<<4)) = make_uint4(0,0,0,0);
    }

    for(int c=0;c<NCH;++c){
        if(c) __syncthreads();          // previous MFMAs done reading LDS
        stage_write();
        __syncthreads();
        if(c+1<NCH) stage_load(c+1);    // T14: issue next chunk's loads early
        const int ic0=c*ICC;
        #pragma unroll
        for(int kk=0;kk<4;++kk){
            const int ky=kk>>1, kx=kk&1;
            int ar[MT];
            #pragma unroll
            for(int m=0;m<MT;++m){
                int p=m*16+l15;
                int py=p/OW, px=p-py*OW;
                int ty=py+ky-PAD, tx=px+kx-PAD;
                bool ok=(p<NPOS)&&((unsigned)ty<(unsigned)IH)&&((unsigned)tx<(unsigned)IW);
                ar[m]= ok ? ty*IW+tx : IHW;
            }
            #pragma unroll
            for(int ks=0;ks<KS;++ks){
                short8v bhv[NT]; short8v blv[SPLIT?NT:1];
                #pragma unroll
                for(int n=0;n<NT;++n){
                    int col=n0+n*16+l15;
                    size_t widx=((size_t)kk*OC+col)*IC+ic0+ks*32+lq*8;
                    bhv[n]=*(const short8v*)(wt_hi+widx);
                    if constexpr(SPLIT) blv[n]=*(const short8v*)(wt_lo+widx);
                }
                #pragma unroll
                for(int m=0;m<MT;++m){
                    int off=ar[m]*RB + ((((ks<<2)|lq)^(ar[m]&7))<<4);
                    short8v ah=*(const short8v*)(sb+off);
                    if constexpr(SPLIT){
                        short8v al=*(const short8v*)(sb+AROWS*RB+off);
                        #pragma unroll
                        for(int n=0;n<NT;++n){
                            acc[m][n]=__builtin_amdgcn_mfma_f32_16x16x32_bf16(ah,bhv[n],acc[m][n],0,0,0);
                            acc[m][n]=__builtin_amdgcn_mfma_f32_16x16x32_bf16(ah,blv[n],acc[m][n],0,0,0);
                            acc[m][n]=__builtin_amdgcn_mfma_f32_16x16x32_bf16(al,bhv[n],acc[m][n],0,0,0);
                        }
                    } else {
                        #pragma unroll
                        for(int n=0;n<NT;++n)
                            acc[m][n]=__builtin_amdgcn_mfma_f32_16x16x32_bf16(ah,bhv[n],acc[m][n],0,0,0);
                    }
                }
            }
        }
    }

    const float rs=(float)(1.0/sqrt(1.0+1e-3));
    float lsum=0.f, colsum=0.f;
    #pragma unroll
    for(int n=0;n<NT;++n){
        int col=n0+n*16+l15;
        float bi=bias[col];
        float gsc=0.f, bt=0.f;
        if constexpr(HASBN){ gsc=gamma[col]*rs; bt=beta[col]; }
        #pragma unroll
        for(int m=0;m<MT;++m){
            #pragma unroll
            for(int j=0;j<4;++j){
                int p=m*16+lq*4+j;
                if(p<NPOS){
                    float vx=acc[m][n][j]+bi;
                    if constexpr(HASBN) vx=fmaxf(fmaf(vx,gsc,bt),0.f);
                    size_t g=(size_t)b*NPOS+p;
                    if constexpr(OUTFMT==0){
                        out_f[g*OC+col]=vx;
                    } else if constexpr(OUTFMT==1){
                        ushort h=bf16_hi(vx);
                        ushort lo=bf16_hi(vx-bf16_tof(h));
                        out_pk[g*OC+col]=(uint)h | ((uint)lo<<16);
                    } else {
                        out_bf[g*OC+col]=bf16_hi(vx);
                    }
                    if constexpr(FUSE){
                        int id=ids[b*L+p];
                        float mm=(masks[b*L+p]>=1)?1.f:0.f;
                        float h=table[(size_t)id*64+col]*mm;
                        float df=h-vx;
                        lsum=fmaf(df,df,lsum);
                        colsum+=vx;
                    }
                }
            }
        }
    }

    if constexpr(FUSE){
        // msum (per-wave redundant)
        float mc=0.f;
        for(int l=lane;l<L;l+=64) mc += (masks[b*L+l]>=1)?1.f:0.f;
        #pragma unroll
        for(int off=32;off;off>>=1) mc+=__shfl_xor(mc,off);
        // vq_mean: combine the 4 lq groups (lanes sharing l15)
        colsum += __shfl_xor(colsum,16);
        colsum += __shfl_xor(colsum,32);
        if(lq==0) out_mean[b*64 + n0 + l15] = colsum/mc;
        // loss1 block reduction
        #pragma unroll
        for(int off=32;off;off>>=1) lsum+=__shfl_xor(lsum,off);
        __syncthreads();
        float* red=(float*)sb;
        if(lane==0) red[wv]=lsum;
        __syncthreads();
        if(tid==0) atomicAdd(acc_g+0, red[0]+red[1]+red[2]+red[3]);
    }
}

// ---------------------------------------------------------------------------
// prep: transpose codebook, code norms, zero accumulators + worklist count
// ---------------------------------------------------------------------------
__global__ __launch_bounds__(256)
void prep_k(const float* __restrict__ book, float* __restrict__ ubt,
            float* __restrict__ cbn, float* __restrict__ acc, int* __restrict__ cnt)
{
    for (int i = threadIdx.x; i < K * CB; i += 256) {
        int k = i >> 9, c = i & 511;
        ubt[c * 64 + k] = book[i];
    }
    if (threadIdx.x < 64) {
        const float* r = book + threadIdx.x * 512;
        float s = 0.f;
        for (int c = 0; c < 512; ++c) s = fmaf(r[c], r[c], s);
        cbn[threadIdx.x] = s;
    }
    if (threadIdx.x < 2) acc[threadIdx.x] = 0.f;
    if (threadIdx.x == 0) *cnt = 0;
}

// ---------------------------------------------------------------------------
// NN search (f32): wave per 4 rows, lane = code. best + runner-up;
// gap <= MARGIN -> worklist for f64 re-verification. loss2 accumulated.
// ---------------------------------------------------------------------------
__global__ __launch_bounds__(256)
void nn_k(const float* __restrict__ xenc, const float* __restrict__ ubt,
          const float* __restrict__ cbn, int* __restrict__ qidx,
          float* __restrict__ acc, int* __restrict__ cnt, int* __restrict__ wl)
{
    const int lane = threadIdx.x & 63;
    const int wave = threadIdx.x >> 6;
    const int wid  = blockIdx.x * 4 + wave;
    const int row0 = wid * 4;
    const float* x0 = xenc + (size_t)row0 * 512;

    float dot[4] = {0.f,0.f,0.f,0.f};
    float xn[4]  = {0.f,0.f,0.f,0.f};
    for (int c = 0; c < 512; ++c) {
        float ub = ubt[c * 64 + lane];
        float a0 = x0[c], a1 = x0[512+c], a2 = x0[1024+c], a3 = x0[1536+c];
        dot[0] = fmaf(a0, ub, dot[0]);  xn[0] = fmaf(a0, a0, xn[0]);
        dot[1] = fmaf(a1, ub, dot[1]);  xn[1] = fmaf(a1, a1, xn[1]);
        dot[2] = fmaf(a2, ub, dot[2]);  xn[2] = fmaf(a2, a2, xn[2]);
        dot[3] = fmaf(a3, ub, dot[3]);  xn[3] = fmaf(a3, a3, xn[3]);
    }

    float l2sum = 0.f;
    #pragma unroll
    for (int j = 0; j < 4; ++j) {
        float d1 = cbn[lane] - 2.f * dot[j];
        int   k1 = lane;
        float d2 = 3.4e38f;
        #pragma unroll
        for (int off = 32; off > 0; off >>= 1) {
            float od1 = __shfl_xor(d1, off);
            int   ok1 = __shfl_xor(k1, off);
            float od2 = __shfl_xor(d2, off);
            if (od1 < d1 || (od1 == d1 && ok1 < k1)) {
                d2 = fminf(d1, od2); d1 = od1; k1 = ok1;
            } else {
                d2 = fminf(d2, od1);
            }
        }
        if (lane == 0) {
            qidx[row0 + j] = k1;
            if (d2 - d1 <= MARGIN) { int t = atomicAdd(cnt, 1); wl[t] = row0 + j; }
            l2sum += d1 + xn[j];
        }
    }
    if (lane == 0) atomicAdd(acc + 1, l2sum);
}

// ---------------------------------------------------------------------------
// f64 re-verification of flagged rows (full receptive field from scratch).
// ---------------------------------------------------------------------------
__global__ __launch_bounds__(256)
void recompute_k(const int* __restrict__ wl, const int* __restrict__ cnt,
                 const int* __restrict__ ids, const int* __restrict__ masks,
                 const float* __restrict__ table, const float* __restrict__ book,
                 const float* __restrict__ e_w1, const float* __restrict__ e_b1,
                 const float* __restrict__ e_g1, const float* __restrict__ e_be1,
                 const float* __restrict__ e_w2, const float* __restrict__ e_b2,
                 const float* __restrict__ e_g2, const float* __restrict__ e_be2,
                 const float* __restrict__ e_w3, const float* __restrict__ e_b3,
                 int* __restrict__ qidx)
{
    __shared__ double s_h[16*64];
    __shared__ double s_a1[9*128];
    __shared__ double s_a2[4*256];
    __shared__ double s_x[512];
    __shared__ double s_d[256];

    const int tid = threadIdx.x;
    const double rs = 1.0 / sqrt(1.0 + 1e-3);
    const int n = *cnt;

    for (int wi = blockIdx.x; wi < n; wi += gridDim.x) {
        const int row = wl[wi];
        const int b = row / 49, p = row % 49;
        const int py = p / 7, px = p % 7;

        for (int i = tid; i < 16*64; i += 256) {
            int cell = i >> 6, d = i & 63;
            int l = (py + (cell >> 2)) * 10 + (px + (cell & 3));
            int id = ids[b*100 + l];
            double m = (masks[b*100 + l] >= 1) ? 1.0 : 0.0;
            s_h[i] = (double)table[(size_t)id*64 + d] * m;
        }
        __syncthreads();

        for (int i = tid; i < 9*128; i += 256) {
            int cell = i >> 7, oc = i & 127;
            int ry = cell / 3, rx = cell % 3;
            double s = 0.0;
            #pragma unroll
            for (int kk = 0; kk < 4; ++kk) {
                int icell = (ry + (kk>>1))*4 + (rx + (kk&1));
                const double* hh = s_h + icell*64;
                const float* ww = e_w1 + (kk*64)*128 + oc;
                for (int ic = 0; ic < 64; ++ic)
                    s = fma(hh[ic], (double)ww[ic*128], s);
            }
            s += (double)e_b1[oc];
            s = s * ((double)e_g1[oc] * rs) + (double)e_be1[oc];
            s_a1[i] = s > 0.0 ? s : 0.0;
        }
        __syncthreads();

        for (int i = tid; i < 4*256; i += 256) {
            int cell = i >> 8, oc = i & 255;
            int qy = cell >> 1, qx = cell & 1;
            double s = 0.0;
            #pragma unroll
            for (int kk = 0; kk < 4; ++kk) {
                int icell = (qy + (kk>>1))*3 + (qx + (kk&1));
                const double* aa = s_a1 + icell*128;
                const float* ww = e_w2 + (kk*128)*256 + oc;
                for (int ic = 0; ic < 128; ++ic)
                    s = fma(aa[ic], (double)ww[ic*256], s);
            }
            s += (double)e_b2[oc];
            s = s * ((double)e_g2[oc] * rs) + (double)e_be2[oc];
            s_a2[i] = s > 0.0 ? s : 0.0;
        }
        __syncthreads();

        for (int i = tid; i < 512; i += 256) {
            double s = 0.0;
            #pragma unroll
            for (int kk = 0; kk < 4; ++kk) {
                const double* aa = s_a2 + kk*256;
                const float* ww = e_w3 + (kk*256)*512 + i;
                for (int ic = 0; ic < 256; ++ic)
                    s = fma(aa[ic], (double)ww[ic*512], s);
            }
            s_x[i] = s + (double)e_b3[i];
        }
        __syncthreads();

        {
            int k = tid & 63, seg = tid >> 6;
            const float* cr = book + k*512 + seg*128;
            const double* xr = s_x + seg*128;
            double s = 0.0;
            for (int c = 0; c < 128; ++c) {
                double dd = xr[c] - (double)cr[c];
                s = fma(dd, dd, s);
            }
            s_d[seg*64 + k] = s;
        }
        __syncthreads();

        if (tid < 64) {
            double dv = s_d[tid] + s_d[64+tid] + s_d[128+tid] + s_d[192+tid];
            int kk2 = tid;
            #pragma unroll
            for (int off = 32; off > 0; off >>= 1) {
                double od = __shfl_xor(dv, off);
                int    ok = __shfl_xor(kk2, off);
                if (od < dv || (od == dv && ok < kk2)) { dv = od; kk2 = ok; }
            }
            if (tid == 0) qidx[row] = kk2;
        }
        __syncthreads();
    }
}

__global__ void loss_k(const float* __restrict__ acc, float* __restrict__ out_loss)
{
    float l1 = acc[0] / 13107200.f;
    float l2 = acc[1] / 51380224.f;
    out_loss[0] = l1 + l2 + 0.25f * l2;
}

// ---------------------------------------------------------------------------
extern "C" void kernel_launch(void* const* d_in, const int* in_sizes, int n_in,
                              void* d_out, int out_size, void* d_ws, size_t ws_size,
                              hipStream_t stream)
{
    const int*   ids   = (const int*)d_in[0];
    const int*   masks = (const int*)d_in[1];
    const float* table = (const float*)d_in[2];
    const float* book  = (const float*)d_in[3];
    const float* e_w1  = (const float*)d_in[4];
    const float* e_b1  = (const float*)d_in[5];
    const float* e_g1  = (const float*)d_in[6];
    const float* e_be1 = (const float*)d_in[7];
    const float* e_w2  = (const float*)d_in[8];
    const float* e_b2  = (const float*)d_in[9];
    const float* e_g2  = (const float*)d_in[10];
    const float* e_be2 = (const float*)d_in[11];
    const float* e_w3  = (const float*)d_in[12];
    const float* e_b3  = (const float*)d_in[13];
    const float* d_w1  = (const float*)d_in[14];
    const float* d_b1  = (const float*)d_in[15];
    const float* d_g1  = (const float*)d_in[16];
    const float* d_be1 = (const float*)d_in[17];
    const float* d_w2  = (const float*)d_in[18];
    const float* d_b2  = (const float*)d_in[19];
    const float* d_g2  = (const float*)d_in[20];
    const float* d_be2 = (const float*)d_in[21];
    const float* d_w3  = (const float*)d_in[22];
    const float* d_b3  = (const float*)d_in[23];

    float*  ws  = (float*)d_ws;
    uint*   A1P = (uint*)(ws + R0_OFF);   // [B*81*128] u32 hi|lo
    uint*   A2P = (uint*)(ws + R1_OFF);   // [B*64*256] u32 hi|lo
    float*  XE  = ws + R0_OFF;            // [B*49*512] f32
    ushort* G1  = (ushort*)(ws + R1_OFF); // [B*64*256] bf16
    ushort* G2  = (ushort*)(ws + R0_OFF); // [B*81*128] bf16
    int*    IDX = (int*)(ws + IDX_OFF);
    float*  UBT = ws + UBT_OFF;
    float*  CBN = ws + CBN_OFF;
    int*    CNT = (int*)(ws + CNT_OFF);
    float*  ACC = ws + ACC_OFF;
    int*    WL  = (int*)(ws + WL_OFF);
    ushort* WB  = (ushort*)(ws + WB_OFF);

    float* out_mean = (float*)d_out;
    float* out_vqx  = (float*)d_out + (size_t)B * 64;
    float* out_loss = (float*)d_out + (size_t)B * 64 + (size_t)B * L * 64;

    prep_k<<<1, 256, 0, stream>>>(book, UBT, CBN, ACC, CNT);
    wprep_k<<<512, 256, 0, stream>>>(e_w1, e_w2, e_w3, d_w1, d_w2, d_w3, book, WB);

    // encoder (split-bf16)
    sconv_k<10,10, 64,128,0,1,true ,true ,1, 64,6,1,false><<<B,   256,0,stream>>>(
        nullptr, nullptr, ids, masks, table, nullptr, nullptr,
        WB+EW1H, WB+EW1L, e_b1, e_g1, e_be1, nullptr, A1P, nullptr, nullptr, nullptr);
    sconv_k< 9, 9,128,256,0,3,true ,true ,2, 64,4,1,false><<<B*2, 256,0,stream>>>(
        A1P, nullptr, nullptr, nullptr, nullptr, nullptr, nullptr,
        WB+EW2H, WB+EW2L, e_b2, e_g2, e_be2, nullptr, A2P, nullptr, nullptr, nullptr);
    sconv_k< 8, 8,256,512,0,3,false,true ,4, 64,4,0,false><<<B*4, 256,0,stream>>>(
        A2P, nullptr, nullptr, nullptr, nullptr, nullptr, nullptr,
        WB+EW3H, WB+EW3L, e_b3, nullptr, nullptr, XE, nullptr, nullptr, nullptr, nullptr);

    // codebook NN (f32 + margin flag) then f64 re-verify of flagged rows
    nn_k<<<6272, 256, 0, stream>>>(XE, UBT, CBN, IDX, ACC, CNT, WL);
    recompute_k<<<512, 256, 0, stream>>>(WL, CNT, ids, masks, table, book,
                                         e_w1, e_b1, e_g1, e_be1,
                                         e_w2, e_b2, e_g2, e_be2,
                                         e_w3, e_b3, IDX);

    // decoder (plain bf16; conv_transpose == conv pad=1, unflipped kernel)
    sconv_k< 7, 7,512,256,1,2,true ,false,2,128,4,2,false><<<B*2, 256,0,stream>>>(
        nullptr, nullptr, nullptr, nullptr, nullptr, IDX, WB+BKB,
        WB+DW1H, nullptr, d_b1, d_g1, d_be1, nullptr, nullptr, G1, nullptr, nullptr);
    sconv_k< 8, 8,256,128,1,4,true ,false,1,128,6,2,false><<<B,   256,0,stream>>>(
        nullptr, G1, nullptr, nullptr, nullptr, nullptr, nullptr,
        WB+DW2H, nullptr, d_b2, d_g2, d_be2, nullptr, nullptr, G2, nullptr, nullptr);
    sconv_k< 9, 9,128, 64,1,4,false,false,1,128,7,0,true ><<<B,   256,0,stream>>>(
        nullptr, G2, ids, masks, table, nullptr, nullptr,
        WB+DW3H, nullptr, d_b3, nullptr, nullptr, out_vqx, nullptr, nullptr, out_mean, ACC);

    loss_k<<<1, 1, 0, stream>>>(ACC, out_loss);
}